// Round 6
// baseline (344.806 us; speedup 1.0000x reference)
//
#include <hip/hip_runtime.h>
#include <hip/hip_bf16.h>

// GemmRS: out[m,n] = sum_{w,k} A[w,m,k]*B[w,n,k]
// A: [8,8192,512] f32, B: [8,1024,512] f32, out: [8192,1024] f32.
//
// R1: dbuf LDS (1 barrier/K-step), bijective XCD swizzle, setprio.
// R2: 128x128 tile, 4 waves, 2 blocks/CU -> cvt ~38us + gemm ~63us.
//     gemm == LDS byte wall: 192 KB/CU/K-step @ ~85 B/cyc = 60us.
// R3: fused f32 reg-staging FAILED (169us): regs across barrier.
// R4: B reg-PREFETCH (cross-barrier liveness) FAILED (146us): same class.
// R5: 2-wave/128thr blocks FAILED (85us): 1 wave/SIMD, no co-wave to hide
//     barrier drain. Rule: >=2 waves/SIMD mandatory.
// R6: R2 structure + B bypasses LDS via SAME-ITERATION global frag loads
//     (no cross-barrier reg liveness -> allocator can't break it).
//     Order: loadB(kt) -> stageA(next) -> ds_read A -> MFMA(vmcnt(4)) -> bar.
//     B slab/block/step = 16 KB, L2-resident (XCD swizzle keeps per-XCD
//     active B k-slab at 128 KB). LDS traffic halves: 192 -> 96 KB/step.

#define WS 8
#define MM 8192
#define KK 512
#define NN 1024
#define KTOT (WS * KK)  // 4096
#define BM 128
#define BN 128
#define BK 64
#define NBLK ((MM / BM) * (NN / BN))  // 512, divisible by 8

#define A_ELEMS ((size_t)WS * MM * KK)  // 33,554,432
#define B_ELEMS ((size_t)WS * NN * KK)  //  4,194,304
#define WS_NEEDED ((A_ELEMS + B_ELEMS) * 2)  // 75,497,472 bytes

typedef __attribute__((ext_vector_type(8))) short short8;
typedef __attribute__((ext_vector_type(4))) short short4v;
typedef __attribute__((ext_vector_type(4))) float floatx4;

static __device__ inline short f2bf(float f) {
    union { __hip_bfloat16 h; short s; } u;
    u.h = __float2bfloat16(f);  // RNE
    return u.s;
}

static __device__ inline void glds16(const short* g, short* l) {
    __builtin_amdgcn_global_load_lds(
        (const __attribute__((address_space(1))) unsigned int*)(uintptr_t)g,
        (__attribute__((address_space(3))) unsigned int*)(uintptr_t)l,
        16, 0, 0);
}

// ---------------- Phase 1: f32 -> bf16 convert (streaming) ----------------
#define CVT_ABLOCKS 16384
#define CVT_NBLOCKS 18432

__global__ __launch_bounds__(256)
void cvt_f32_bf16(const float* __restrict__ A, const float* __restrict__ B,
                  short* __restrict__ Abf, short* __restrict__ Bbf) {
    const float* src;
    short* dst;
    size_t base;
    if (blockIdx.x < CVT_ABLOCKS) {
        src = A; dst = Abf;
        base = ((size_t)blockIdx.x * 256 + threadIdx.x) * 8;
    } else {
        src = B; dst = Bbf;
        base = ((size_t)(blockIdx.x - CVT_ABLOCKS) * 256 + threadIdx.x) * 8;
    }
    float4 v0 = *(const float4*)(src + base);
    float4 v1 = *(const float4*)(src + base + 4);
    short8 o = { f2bf(v0.x), f2bf(v0.y), f2bf(v0.z), f2bf(v0.w),
                 f2bf(v1.x), f2bf(v1.y), f2bf(v1.z), f2bf(v1.w) };
    *(short8*)(dst + base) = o;
}

// ---------------- Phase 2: bf16 GEMM 128x128, A in LDS, B direct ----------
// 4 waves: wr in {0,1} (64 rows), wc in {0,1} (64 cols); 4x4 frags/wave,
// 32 MFMA/wave/K-step. LDS = A only: 2 x 16 KB.
__global__ __launch_bounds__(256, 2)
void gemm_bf16_rs(const short* __restrict__ Abf, const short* __restrict__ Bbf,
                  float* __restrict__ C) {
    __shared__ short As[2][BM * BK];  // 32 KB total

    const int tid  = threadIdx.x;
    const int lane = tid & 63;
    const int wid  = tid >> 6;

    // Bijective XCD swizzle: XCD j owns 64 consecutive tiles = 8 contiguous
    // M-panel rows (A 8 MB + B 8.4 MB per-XCD working set).
    const int lin = blockIdx.y * gridDim.x + blockIdx.x;       // 0..511
    const int T   = (lin & 7) * (NBLK / 8) + (lin >> 3);       // bijective
    const int ty  = T >> 3;          // 0..63  (M tile)
    const int tx  = T & 7;           // 0..7   (N tile)
    const int m0  = ty * BM;
    const int n0  = tx * BN;

    const int wr = wid >> 1, wc = wid & 1;
    const int lm = lane & 15, quad = lane >> 4;

    // A staging geometry (R2-identical): chunk = 64 lanes x 16B = 8 rows x
    // 8 segs; stored seg p of row r holds logical seg p^(r&7).
    const int lrow = lane >> 3;
    const int ss   = (lane & 7) ^ lrow;

    size_t gA[4];
#pragma unroll
    for (int t = 0; t < 4; ++t)
        gA[t] = (size_t)(m0 + wid * 32 + t * 8 + lrow) * KK + ss * 8;

    // B direct-frag offsets within a rank bank: lane's frag (kc,j) is the
    // 16 contiguous bytes B[n0 + wc*64 + j*16 + lm][kk + kc*32 + quad*8 ..+7]
    // -- identical bytes to what R2 read from LDS (swizzle cancels).
    size_t gB[4];
#pragma unroll
    for (int j = 0; j < 4; ++j)
        gB[j] = (size_t)(n0 + wc * 64 + j * 16 + lm) * KK + quad * 8;

    floatx4 acc[4][4];
#pragma unroll
    for (int i = 0; i < 4; ++i)
#pragma unroll
        for (int j = 0; j < 4; ++j) acc[i][j] = (floatx4)0.f;

    auto stageA = [&](int buf, int kt) {
        const int w  = kt >> 9;         // rank bank (uniform)
        const int kk = kt & (KK - 1);   // offset inside bank (uniform)
        const short* Aw = Abf + (size_t)w * MM * KK + kk;
#pragma unroll
        for (int t = 0; t < 4; ++t)
            glds16(Aw + gA[t], &As[buf][(wid * 4 + t) * 512 + lane * 8]);
    };

    // Prologue: stage A tile 0; barrier's vmcnt(0) drain makes it ready.
    stageA(0, 0);
    __syncthreads();

    for (int kt = 0; kt < KTOT; kt += BK) {
        const int cur = (kt >> 6) & 1;

        // (1) B fragment loads for THIS K-step, issued first so the MFMA's
        //     wait is vmcnt(4) (the 4 younger A-glds keep flying).
        short8 bfr[2][4];
        {
            const int w  = kt >> 9;
            const int kk = kt & (KK - 1);
            const short* Bw = Bbf + (size_t)w * NN * KK + kk;
#pragma unroll
            for (int kc = 0; kc < 2; ++kc)
#pragma unroll
                for (int j = 0; j < 4; ++j)
                    bfr[kc][j] = *(const short8*)(Bw + gB[j] + kc * 32);
        }

        // (2) Next A tile -> other LDS buffer (glds: no dest regs, cannot
        //     be sunk or spilled; completes at the end-of-iter barrier).
        if (kt + BK < KTOT) stageA(cur ^ 1, kt + BK);

        // (3) A fragments from LDS.
        short8 af[2][4];
#pragma unroll
        for (int kc = 0; kc < 2; ++kc)
#pragma unroll
            for (int i = 0; i < 4; ++i) {
                const int row = wr * 64 + i * 16 + lm;
                const int sa  = (kc * 4 + quad) ^ (lm & 7);
                af[kc][i] = *(const short8*)&As[cur][row * BK + sa * 8];
            }

        // (4) MFMA (compiler emits vmcnt(4) + lgkmcnt for the frag deps).
        __builtin_amdgcn_s_setprio(1);
#pragma unroll
        for (int kc = 0; kc < 2; ++kc)
#pragma unroll
            for (int i = 0; i < 4; ++i)
#pragma unroll
                for (int j = 0; j < 4; ++j)
                    acc[i][j] = __builtin_amdgcn_mfma_f32_16x16x32_bf16(
                        af[kc][i], bfr[kc][j], acc[i][j], 0, 0, 0);
        __builtin_amdgcn_s_setprio(0);
        __syncthreads();  // drains vmcnt (A staged) + lgkm (reads done)
    }

    // Epilogue: C/D layout col = lane&15 (n), row = quad*4 + r (m) [m89]
#pragma unroll
    for (int i = 0; i < 4; ++i)
#pragma unroll
        for (int j = 0; j < 4; ++j) {
            const int n = n0 + wc * 64 + j * 16 + lm;
#pragma unroll
            for (int r = 0; r < 4; ++r) {
                const int m = m0 + wr * 64 + i * 16 + quad * 4 + r;
                C[(size_t)m * NN + n] = acc[i][j][r];
            }
        }
}

// ---------------- Fallback (ws too small): f32-input fused kernel ----------
__global__ __launch_bounds__(256, 2)
void gemm_rs_fused(const float* __restrict__ A, const float* __restrict__ B,
                   float* __restrict__ C) {
    __shared__ short As[128 * 32];
    __shared__ short Bs[128 * 32];
    const int tid = threadIdx.x;
    const int m0 = blockIdx.y * 128;
    const int n0 = blockIdx.x * 128;
    const int wid = tid >> 6, lane = tid & 63;
    const int wr = wid >> 1, wc = wid & 1;
    const int lm = lane & 15, quad = lane >> 4;
    floatx4 acc[4][4];
#pragma unroll
    for (int i = 0; i < 4; ++i)
#pragma unroll
        for (int j = 0; j < 4; ++j) acc[i][j] = (floatx4)0.f;
    for (int kt = 0; kt < KTOT; kt += 32) {
        const int w = kt >> 9, kk = kt & (KK - 1);
        const float* Aw = A + (size_t)w * MM * KK;
        const float* Bw = B + (size_t)w * NN * KK;
        __syncthreads();
#pragma unroll
        for (int i = 0; i < 4; ++i) {
            const int idx = i * 256 + tid;
            const int row = idx >> 3;
            const int c4 = (idx & 7) * 4;
            float4 av = *(const float4*)&Aw[(size_t)(m0 + row) * KK + kk + c4];
            float4 bv = *(const float4*)&Bw[(size_t)(n0 + row) * KK + kk + c4];
            short4v a4 = { f2bf(av.x), f2bf(av.y), f2bf(av.z), f2bf(av.w) };
            short4v b4 = { f2bf(bv.x), f2bf(bv.y), f2bf(bv.z), f2bf(bv.w) };
            *(short4v*)&As[row * 32 + c4] = a4;
            *(short4v*)&Bs[row * 32 + c4] = b4;
        }
        __syncthreads();
        short8 af[4], bfr[4];
#pragma unroll
        for (int i = 0; i < 4; ++i)
            af[i] = *(const short8*)&As[(wr * 64 + i * 16 + lm) * 32 + quad * 8];
#pragma unroll
        for (int j = 0; j < 4; ++j)
            bfr[j] = *(const short8*)&Bs[(wc * 64 + j * 16 + lm) * 32 + quad * 8];
#pragma unroll
        for (int i = 0; i < 4; ++i)
#pragma unroll
            for (int j = 0; j < 4; ++j)
                acc[i][j] = __builtin_amdgcn_mfma_f32_16x16x32_bf16(
                    af[i], bfr[j], acc[i][j], 0, 0, 0);
    }
#pragma unroll
    for (int i = 0; i < 4; ++i)
#pragma unroll
        for (int j = 0; j < 4; ++j) {
            const int n = n0 + wc * 64 + j * 16 + lm;
#pragma unroll
            for (int r = 0; r < 4; ++r) {
                const int m = m0 + wr * 64 + i * 16 + quad * 4 + r;
                C[(size_t)m * NN + n] = acc[i][j][r];
            }
        }
}

extern "C" void kernel_launch(void* const* d_in, const int* in_sizes, int n_in,
                              void* d_out, int out_size, void* d_ws, size_t ws_size,
                              hipStream_t stream) {
    const float* A = (const float*)d_in[0];  // [8,8192,512]
    const float* B = (const float*)d_in[1];  // [8,1024,512]
    float* C = (float*)d_out;                // [8192,1024]

    if (ws_size >= WS_NEEDED) {
        short* Abf = (short*)d_ws;
        short* Bbf = Abf + A_ELEMS;
        cvt_f32_bf16<<<CVT_NBLOCKS, 256, 0, stream>>>(A, B, Abf, Bbf);
        dim3 grid(NN / BN, MM / BM);  // (8, 64) = 512 blocks
        gemm_bf16_rs<<<grid, 256, 0, stream>>>(Abf, Bbf, C);
    } else {
        dim3 grid(NN / 128, MM / 128);  // (8, 64)
        gemm_rs_fused<<<grid, 256, 0, stream>>>(A, B, C);
    }
}

// Round 7
// 273.705 us; speedup vs baseline: 1.2598x; 1.2598x over previous
//
#include <hip/hip_runtime.h>
#include <hip/hip_bf16.h>

// GemmRS: out[m,n] = sum_{w,k} A[w,m,k]*B[w,n,k]
// A: [8,8192,512] f32, B: [8,1024,512] f32, out: [8192,1024] f32.
//
// R1: dbuf LDS (1 barrier/K-step), bijective XCD swizzle, setprio.
// R2: 128x128 tile, 4 waves, 2 blocks/CU -> cvt ~38us + gemm ~63us.
//     gemm == LDS byte wall: 96KB/block/K-step = 21.8 FLOP/B @ ~85 B/cyc.
// R3: fused f32 reg-staging FAILED (169us): regs across barrier.
// R4: B reg-PREFETCH FAILED (146us): cross-barrier reg liveness.
// R5: 2-wave/128thr FAILED (85us): 1 wave/SIMD. Rule: >=2 waves/SIMD.
// R6: B same-iter global->VGPR frags FAILED (145us): hipcc exposes VMEM
//     latency per iter. RULE (3 strikes): operands ONLY via glds->LDS->ds_read.
// R7: BM=256 BN=128, 512 thr, 8 waves = 2(M) x 2(N) x 2(K-split).
//     Wave tile 128x64; kg half computes k in [kg*32, kg*32+32) of BK=64;
//     partial accs merged via LDS after the K-loop. 29.1 FLOP/LDS-byte
//     (+33% vs R2), glds-only staging, 2 waves/SIMD, 1 block/CU (96KB LDS).

#define WS 8
#define MM 8192
#define KK 512
#define NN 1024
#define KTOT (WS * KK)  // 4096
#define BM 256
#define BN 128
#define BK 64
#define NBLK ((MM / BM) * (NN / BN))  // 256, divisible by 8

#define A_ELEMS ((size_t)WS * MM * KK)  // 33,554,432
#define B_ELEMS ((size_t)WS * NN * KK)  //  4,194,304
#define WS_NEEDED ((A_ELEMS + B_ELEMS) * 2)  // 75,497,472 bytes

typedef __attribute__((ext_vector_type(8))) short short8;
typedef __attribute__((ext_vector_type(4))) short short4v;
typedef __attribute__((ext_vector_type(4))) float floatx4;

static __device__ inline short f2bf(float f) {
    union { __hip_bfloat16 h; short s; } u;
    u.h = __float2bfloat16(f);  // RNE
    return u.s;
}

static __device__ inline void glds16(const short* g, short* l) {
    __builtin_amdgcn_global_load_lds(
        (const __attribute__((address_space(1))) unsigned int*)(uintptr_t)g,
        (__attribute__((address_space(3))) unsigned int*)(uintptr_t)l,
        16, 0, 0);
}

// ---------------- Phase 1: f32 -> bf16 convert (streaming) ----------------
#define CVT_ABLOCKS 16384
#define CVT_NBLOCKS 18432

__global__ __launch_bounds__(256)
void cvt_f32_bf16(const float* __restrict__ A, const float* __restrict__ B,
                  short* __restrict__ Abf, short* __restrict__ Bbf) {
    const float* src;
    short* dst;
    size_t base;
    if (blockIdx.x < CVT_ABLOCKS) {
        src = A; dst = Abf;
        base = ((size_t)blockIdx.x * 256 + threadIdx.x) * 8;
    } else {
        src = B; dst = Bbf;
        base = ((size_t)(blockIdx.x - CVT_ABLOCKS) * 256 + threadIdx.x) * 8;
    }
    float4 v0 = *(const float4*)(src + base);
    float4 v1 = *(const float4*)(src + base + 4);
    short8 o = { f2bf(v0.x), f2bf(v0.y), f2bf(v0.z), f2bf(v0.w),
                 f2bf(v1.x), f2bf(v1.y), f2bf(v1.z), f2bf(v1.w) };
    *(short8*)(dst + base) = o;
}

// ---------------- Phase 2: bf16 GEMM 256x128, 8 waves, K-split ------------
// wid bits: wr = (wid>>2)&1 (M half), wc = (wid>>1)&1 (N half), kg = wid&1
// (K half of the BK=64 step). Per wave: 8 m-frags x 4 n-frags x 1 kc = 32
// MFMA/K-step on its kg half. After the loop, kg=1 partials are added into
// kg=0 accs via LDS (2 rounds), kg=0 waves write C.
__global__ __launch_bounds__(512, 2)
void gemm_bf16_rs(const short* __restrict__ Abf, const short* __restrict__ Bbf,
                  float* __restrict__ C) {
    __shared__ short As[2][BM * BK];  // 64 KB
    __shared__ short Bs[2][BN * BK];  // 32 KB

    const int tid  = threadIdx.x;
    const int lane = tid & 63;
    const int wid  = tid >> 6;       // 0..7

    // Bijective XCD swizzle: XCD j owns 32 consecutive tiles = 4 contiguous
    // M-panel rows (all 8 N-tiles each).
    const int lin = blockIdx.y * gridDim.x + blockIdx.x;       // 0..255
    const int T   = (lin & 7) * (NBLK / 8) + (lin >> 3);       // bijective
    const int ty  = T >> 3;          // 0..31  (M tile)
    const int tx  = T & 7;           // 0..7   (N tile)
    const int m0  = ty * BM;
    const int n0  = tx * BN;

    const int wr = (wid >> 2) & 1, wc = (wid >> 1) & 1, kg = wid & 1;
    const int lm = lane & 15, quad = lane >> 4;

    // Staging geometry (R2-identical pattern): chunk = 64 lanes x 16B =
    // 8 rows x 8 segs (seg = 8 bf16); stored seg p of row r holds logical
    // seg p ^ (r&7); frag reads compensate with the same XOR.
    const int lrow = lane >> 3;
    const int ss   = (lane & 7) ^ lrow;

    // A: 32 chunks (256 rows), 4/wave. B: 16 chunks (128 rows), 2/wave.
    size_t gA[4], gB[2];
#pragma unroll
    for (int t = 0; t < 4; ++t)
        gA[t] = (size_t)(m0 + wid * 32 + t * 8 + lrow) * KK + ss * 8;
#pragma unroll
    for (int t = 0; t < 2; ++t)
        gB[t] = (size_t)(n0 + wid * 16 + t * 8 + lrow) * KK + ss * 8;

    floatx4 acc[8][4];
#pragma unroll
    for (int i = 0; i < 8; ++i)
#pragma unroll
        for (int j = 0; j < 4; ++j) acc[i][j] = (floatx4)0.f;

    auto stage = [&](int buf, int kt) {
        const int w  = kt >> 9;         // rank bank (uniform)
        const int kk = kt & (KK - 1);   // offset inside bank (uniform)
        const short* Aw = Abf + (size_t)w * MM * KK + kk;
        const short* Bw = Bbf + (size_t)w * NN * KK + kk;
#pragma unroll
        for (int t = 0; t < 4; ++t)
            glds16(Aw + gA[t], &As[buf][(wid * 4 + t) * 512 + lane * 8]);
#pragma unroll
        for (int t = 0; t < 2; ++t)
            glds16(Bw + gB[t], &Bs[buf][(wid * 2 + t) * 512 + lane * 8]);
    };

    // Prologue: stage tile 0; barrier's vmcnt(0) drain makes it ready.
    stage(0, 0);
    __syncthreads();

    for (int kt = 0; kt < KTOT; kt += BK) {
        const int cur = (kt >> 6) & 1;
        // Next tile's staging first (glds: no dest regs -> cannot be sunk
        // or spilled). Completes at the end-of-iter barrier.
        if (kt + BK < KTOT) stage(cur ^ 1, kt + BK);

        // This wave's kg-half fragments. row&7 == lm&7 (offsets are
        // multiples of 16), so the seg XOR is (lm&7).
        short8 af[8], bfr[4];
        const int sk = (kg * 4 + quad);          // logical k-seg 0..7
#pragma unroll
        for (int i = 0; i < 8; ++i) {
            const int row = wr * 128 + i * 16 + lm;
            af[i] = *(const short8*)&As[cur][row * BK + (sk ^ (lm & 7)) * 8];
        }
#pragma unroll
        for (int j = 0; j < 4; ++j) {
            const int row = wc * 64 + j * 16 + lm;
            bfr[j] = *(const short8*)&Bs[cur][row * BK + (sk ^ (lm & 7)) * 8];
        }

        __builtin_amdgcn_s_setprio(1);
#pragma unroll
        for (int i = 0; i < 8; ++i)
#pragma unroll
            for (int j = 0; j < 4; ++j)
                acc[i][j] = __builtin_amdgcn_mfma_f32_16x16x32_bf16(
                    af[i], bfr[j], acc[i][j], 0, 0, 0);
        __builtin_amdgcn_s_setprio(0);
        __syncthreads();  // drains vmcnt (next tile staged) + lgkm
    }

    // ---- K-split merge: kg=1 waves add their partials into kg=0's accs.
    // 2 rounds of 4 i-frags; LDS scratch = As (16384 floats). Layout
    // lane-fastest (conflict-free b32): S[slot*4096 + idx*64 + lane].
    {
        float* S = (float*)As;
        const int slot = wid >> 1;  // 0..3, same for partner pair
#pragma unroll
        for (int half = 0; half < 2; ++half) {
            __syncthreads();
            if (kg == 1) {
#pragma unroll
                for (int ii = 0; ii < 4; ++ii)
#pragma unroll
                    for (int j = 0; j < 4; ++j)
#pragma unroll
                        for (int r = 0; r < 4; ++r)
                            S[slot * 4096 + (ii * 16 + j * 4 + r) * 64 + lane]
                                = acc[half * 4 + ii][j][r];
            }
            __syncthreads();
            if (kg == 0) {
#pragma unroll
                for (int ii = 0; ii < 4; ++ii)
#pragma unroll
                    for (int j = 0; j < 4; ++j)
#pragma unroll
                        for (int r = 0; r < 4; ++r)
                            acc[half * 4 + ii][j][r] +=
                                S[slot * 4096 + (ii * 16 + j * 4 + r) * 64 + lane];
            }
        }
    }

    // Epilogue (kg=0 waves): C/D layout col = lane&15 (n), row = quad*4+r [m89]
    if (kg == 0) {
#pragma unroll
        for (int i = 0; i < 8; ++i)
#pragma unroll
            for (int j = 0; j < 4; ++j) {
                const int n = n0 + wc * 64 + j * 16 + lm;
#pragma unroll
                for (int r = 0; r < 4; ++r) {
                    const int m = m0 + wr * 128 + i * 16 + quad * 4 + r;
                    C[(size_t)m * NN + n] = acc[i][j][r];
                }
            }
    }
}

// ---------------- Fallback (ws too small): f32-input fused kernel ----------
__global__ __launch_bounds__(256, 2)
void gemm_rs_fused(const float* __restrict__ A, const float* __restrict__ B,
                   float* __restrict__ C) {
    __shared__ short As[128 * 32];
    __shared__ short Bs[128 * 32];
    const int tid = threadIdx.x;
    const int m0 = blockIdx.y * 128;
    const int n0 = blockIdx.x * 128;
    const int wid = tid >> 6, lane = tid & 63;
    const int wr = wid >> 1, wc = wid & 1;
    const int lm = lane & 15, quad = lane >> 4;
    floatx4 acc[4][4];
#pragma unroll
    for (int i = 0; i < 4; ++i)
#pragma unroll
        for (int j = 0; j < 4; ++j) acc[i][j] = (floatx4)0.f;
    for (int kt = 0; kt < KTOT; kt += 32) {
        const int w = kt >> 9, kk = kt & (KK - 1);
        const float* Aw = A + (size_t)w * MM * KK;
        const float* Bw = B + (size_t)w * NN * KK;
        __syncthreads();
#pragma unroll
        for (int i = 0; i < 4; ++i) {
            const int idx = i * 256 + tid;
            const int row = idx >> 3;
            const int c4 = (idx & 7) * 4;
            float4 av = *(const float4*)&Aw[(size_t)(m0 + row) * KK + kk + c4];
            float4 bv = *(const float4*)&Bw[(size_t)(n0 + row) * KK + kk + c4];
            short4v a4 = { f2bf(av.x), f2bf(av.y), f2bf(av.z), f2bf(av.w) };
            short4v b4 = { f2bf(bv.x), f2bf(bv.y), f2bf(bv.z), f2bf(bv.w) };
            *(short4v*)&As[row * 32 + c4] = a4;
            *(short4v*)&Bs[row * 32 + c4] = b4;
        }
        __syncthreads();
        short8 af[4], bfr[4];
#pragma unroll
        for (int i = 0; i < 4; ++i)
            af[i] = *(const short8*)&As[(wr * 64 + i * 16 + lm) * 32 + quad * 8];
#pragma unroll
        for (int j = 0; j < 4; ++j)
            bfr[j] = *(const short8*)&Bs[(wc * 64 + j * 16 + lm) * 32 + quad * 8];
#pragma unroll
        for (int i = 0; i < 4; ++i)
#pragma unroll
            for (int j = 0; j < 4; ++j)
                acc[i][j] = __builtin_amdgcn_mfma_f32_16x16x32_bf16(
                    af[i], bfr[j], acc[i][j], 0, 0, 0);
    }
#pragma unroll
    for (int i = 0; i < 4; ++i)
#pragma unroll
        for (int j = 0; j < 4; ++j) {
            const int n = n0 + wc * 64 + j * 16 + lm;
#pragma unroll
            for (int r = 0; r < 4; ++r) {
                const int m = m0 + wr * 64 + i * 16 + quad * 4 + r;
                C[(size_t)m * NN + n] = acc[i][j][r];
            }
        }
}

extern "C" void kernel_launch(void* const* d_in, const int* in_sizes, int n_in,
                              void* d_out, int out_size, void* d_ws, size_t ws_size,
                              hipStream_t stream) {
    const float* A = (const float*)d_in[0];  // [8,8192,512]
    const float* B = (const float*)d_in[1];  // [8,1024,512]
    float* C = (float*)d_out;                // [8192,1024]

    if (ws_size >= WS_NEEDED) {
        short* Abf = (short*)d_ws;
        short* Bbf = Abf + A_ELEMS;
        cvt_f32_bf16<<<CVT_NBLOCKS, 256, 0, stream>>>(A, B, Abf, Bbf);
        dim3 grid(NN / BN, MM / BM);  // (8, 32) = 256 blocks, 1/CU
        gemm_bf16_rs<<<grid, 512, 0, stream>>>(Abf, Bbf, C);
    } else {
        dim3 grid(NN / 128, MM / 128);  // (8, 64)
        gemm_rs_fused<<<grid, 256, 0, stream>>>(A, B, C);
    }
}

// Round 8
// 273.365 us; speedup vs baseline: 1.2613x; 1.0012x over previous
//
#include <hip/hip_runtime.h>
#include <hip/hip_bf16.h>

// GemmRS: out[m,n] = sum_{w,k} A[w,m,k]*B[w,n,k]
// A: [8,8192,512] f32, B: [8,1024,512] f32, out: [8192,1024] f32.
//
// FINAL (R8 = exact R2 restore). Session ledger:
// R1: dbuf LDS (1 barrier/K-step), bijective XCD swizzle, setprio.
//     FETCH 276->108 MB (compulsory), gemm 98->92.6us.
// R2: 128x128 tile, 4 waves, 2 blocks/CU -> cvt ~38us + gemm ~63us.
//     gemm at LDS byte wall: 192 KB/CU/K-step @ ~85 B/cyc = 60us model.
//     BEST KNOWN: 271.2us total.
// R3: fused f32 reg-staging FAILED (169us): hipcc won't hold staging regs
//     across barriers (spill/sink serialization).
// R4: B reg-PREFETCH FAILED (146us): same cross-barrier liveness class.
// R5: 2-wave/128thr FAILED (85us): 1 wave/SIMD. Rule: >=2 waves/SIMD.
// R6: B same-iter global->VGPR frags FAILED (145us): hipcc exposes VMEM
//     latency per iter. Rule: operands ONLY via glds->LDS->ds_read.
// R7: 256x128 K-split 8-wave FAILED (80.6us): 1 block/CU -> barrier drain
//     exposed every step. Rule: >=2 blocks/CU.
// Geometry search under all rules: FLOP/LDS-byte = BM*BN/[(BM+BN)+Rn*BM+Rm*BN]
// maximized by exactly this config (21.3). gemm = 95% of its LDS wall;
// cvt = HBM roofline (227 MB). Structurally converged.

#define WS 8
#define MM 8192
#define KK 512
#define NN 1024
#define KTOT (WS * KK)  // 4096
#define BM 128
#define BN 128
#define BK 64
#define NBLK ((MM / BM) * (NN / BN))  // 512, divisible by 8

#define A_ELEMS ((size_t)WS * MM * KK)  // 33,554,432
#define B_ELEMS ((size_t)WS * NN * KK)  //  4,194,304
#define WS_NEEDED ((A_ELEMS + B_ELEMS) * 2)  // 75,497,472 bytes

typedef __attribute__((ext_vector_type(8))) short short8;
typedef __attribute__((ext_vector_type(4))) short short4v;
typedef __attribute__((ext_vector_type(4))) float floatx4;

static __device__ inline short f2bf(float f) {
    union { __hip_bfloat16 h; short s; } u;
    u.h = __float2bfloat16(f);  // RNE
    return u.s;
}

static __device__ inline void glds16(const short* g, short* l) {
    __builtin_amdgcn_global_load_lds(
        (const __attribute__((address_space(1))) unsigned int*)(uintptr_t)g,
        (__attribute__((address_space(3))) unsigned int*)(uintptr_t)l,
        16, 0, 0);
}

// ---------------- Phase 1: f32 -> bf16 convert (streaming) ----------------
#define CVT_ABLOCKS 16384
#define CVT_NBLOCKS 18432

__global__ __launch_bounds__(256)
void cvt_f32_bf16(const float* __restrict__ A, const float* __restrict__ B,
                  short* __restrict__ Abf, short* __restrict__ Bbf) {
    const float* src;
    short* dst;
    size_t base;
    if (blockIdx.x < CVT_ABLOCKS) {
        src = A; dst = Abf;
        base = ((size_t)blockIdx.x * 256 + threadIdx.x) * 8;
    } else {
        src = B; dst = Bbf;
        base = ((size_t)(blockIdx.x - CVT_ABLOCKS) * 256 + threadIdx.x) * 8;
    }
    float4 v0 = *(const float4*)(src + base);
    float4 v1 = *(const float4*)(src + base + 4);
    short8 o = { f2bf(v0.x), f2bf(v0.y), f2bf(v0.z), f2bf(v0.w),
                 f2bf(v1.x), f2bf(v1.y), f2bf(v1.z), f2bf(v1.w) };
    *(short8*)(dst + base) = o;
}

// ---------------- Phase 2: bf16 GEMM 128x128 (dbuf + XCD swizzle) ---------
// 4 waves: wr in {0,1} (64 rows), wc in {0,1} (64 cols); 4x4 frags/wave,
// 32 MFMA/wave/K-step.
__global__ __launch_bounds__(256, 2)
void gemm_bf16_rs(const short* __restrict__ Abf, const short* __restrict__ Bbf,
                  float* __restrict__ C) {
    __shared__ short As[2][BM * BK];  // 32 KB
    __shared__ short Bs[2][BN * BK];  // 32 KB

    const int tid  = threadIdx.x;
    const int lane = tid & 63;
    const int wid  = tid >> 6;

    // Bijective XCD swizzle: XCD j owns 64 consecutive tiles = 8 contiguous
    // M-panel rows (8 MB A-panel + 8.4 MB B working set per XCD).
    const int lin = blockIdx.y * gridDim.x + blockIdx.x;       // 0..511
    const int T   = (lin & 7) * (NBLK / 8) + (lin >> 3);       // bijective
    const int ty  = T >> 3;          // 0..63  (M tile)
    const int tx  = T & 7;           // 0..7   (N tile)
    const int m0  = ty * BM;
    const int n0  = tx * BN;

    const int wr = wid >> 1, wc = wid & 1;
    const int lm = lane & 15, quad = lane >> 4;

    // Staging geometry: chunk = 64 lanes x 16B = 8 rows x 8 segs (seg = 8
    // bf16). Stored seg p of row r holds logical seg p ^ (r&7); frag reads
    // compensate with the same XOR.
    const int lrow = lane >> 3;
    const int ss   = (lane & 7) ^ lrow;

    size_t gA[4], gB[4];
#pragma unroll
    for (int t = 0; t < 4; ++t) {
        gA[t] = (size_t)(m0 + wid * 32 + t * 8 + lrow) * KK + ss * 8;
        gB[t] = (size_t)(n0 + wid * 32 + t * 8 + lrow) * KK + ss * 8;
    }

    floatx4 acc[4][4];
#pragma unroll
    for (int i = 0; i < 4; ++i)
#pragma unroll
        for (int j = 0; j < 4; ++j) acc[i][j] = (floatx4)0.f;

    auto stage = [&](int buf, int kt) {
        const int w  = kt >> 9;         // rank bank (uniform)
        const int kk = kt & (KK - 1);   // offset inside bank (uniform)
        const short* Aw = Abf + (size_t)w * MM * KK + kk;
        const short* Bw = Bbf + (size_t)w * NN * KK + kk;
#pragma unroll
        for (int t = 0; t < 4; ++t)
            glds16(Aw + gA[t], &As[buf][(wid * 4 + t) * 512 + lane * 8]);
#pragma unroll
        for (int t = 0; t < 4; ++t)
            glds16(Bw + gB[t], &Bs[buf][(wid * 4 + t) * 512 + lane * 8]);
    };

    // Prologue: stage tile 0; barrier's vmcnt(0) drain makes it ready.
    stage(0, 0);
    __syncthreads();

    for (int kt = 0; kt < KTOT; kt += BK) {
        const int cur = (kt >> 6) & 1;
        // Issue next tile's staging FIRST (glds: no dest regs, cannot be
        // sunk or spilled). Latency hides under the ds_read + MFMA below;
        // single end-of-iter barrier.
        if (kt + BK < KTOT) stage(cur ^ 1, kt + BK);

        short8 af[2][4], bfr[2][4];
#pragma unroll
        for (int kc = 0; kc < 2; ++kc) {
#pragma unroll
            for (int i = 0; i < 4; ++i) {
                const int row = wr * 64 + i * 16 + lm;
                const int sa  = (kc * 4 + quad) ^ (lm & 7);
                af[kc][i] = *(const short8*)&As[cur][row * BK + sa * 8];
            }
#pragma unroll
            for (int j = 0; j < 4; ++j) {
                const int row = wc * 64 + j * 16 + lm;
                const int sb  = (kc * 4 + quad) ^ (lm & 7);
                bfr[kc][j] = *(const short8*)&Bs[cur][row * BK + sb * 8];
            }
        }
        __builtin_amdgcn_s_setprio(1);
#pragma unroll
        for (int kc = 0; kc < 2; ++kc)
#pragma unroll
            for (int i = 0; i < 4; ++i)
#pragma unroll
                for (int j = 0; j < 4; ++j)
                    acc[i][j] = __builtin_amdgcn_mfma_f32_16x16x32_bf16(
                        af[kc][i], bfr[kc][j], acc[i][j], 0, 0, 0);
        __builtin_amdgcn_s_setprio(0);
        __syncthreads();  // drains vmcnt (next tile staged) + lgkm
    }

    // Epilogue: C/D layout col = lane&15 (n), row = quad*4 + r (m) [m89]
#pragma unroll
    for (int i = 0; i < 4; ++i)
#pragma unroll
        for (int j = 0; j < 4; ++j) {
            const int n = n0 + wc * 64 + j * 16 + lm;
#pragma unroll
            for (int r = 0; r < 4; ++r) {
                const int m = m0 + wr * 64 + i * 16 + quad * 4 + r;
                C[(size_t)m * NN + n] = acc[i][j][r];
            }
        }
}

// ---------------- Fallback (ws too small): f32-input fused kernel ----------
__global__ __launch_bounds__(256, 2)
void gemm_rs_fused(const float* __restrict__ A, const float* __restrict__ B,
                   float* __restrict__ C) {
    __shared__ short As[128 * 32];
    __shared__ short Bs[128 * 32];
    const int tid = threadIdx.x;
    const int m0 = blockIdx.y * 128;
    const int n0 = blockIdx.x * 128;
    const int wid = tid >> 6, lane = tid & 63;
    const int wr = wid >> 1, wc = wid & 1;
    const int lm = lane & 15, quad = lane >> 4;
    floatx4 acc[4][4];
#pragma unroll
    for (int i = 0; i < 4; ++i)
#pragma unroll
        for (int j = 0; j < 4; ++j) acc[i][j] = (floatx4)0.f;
    for (int kt = 0; kt < KTOT; kt += 32) {
        const int w = kt >> 9, kk = kt & (KK - 1);
        const float* Aw = A + (size_t)w * MM * KK;
        const float* Bw = B + (size_t)w * NN * KK;
        __syncthreads();
#pragma unroll
        for (int i = 0; i < 4; ++i) {
            const int idx = i * 256 + tid;
            const int row = idx >> 3;
            const int c4 = (idx & 7) * 4;
            float4 av = *(const float4*)&Aw[(size_t)(m0 + row) * KK + kk + c4];
            float4 bv = *(const float4*)&Bw[(size_t)(n0 + row) * KK + kk + c4];
            short4v a4 = { f2bf(av.x), f2bf(av.y), f2bf(av.z), f2bf(av.w) };
            short4v b4 = { f2bf(bv.x), f2bf(bv.y), f2bf(bv.z), f2bf(bv.w) };
            *(short4v*)&As[row * 32 + c4] = a4;
            *(short4v*)&Bs[row * 32 + c4] = b4;
        }
        __syncthreads();
        short8 af[4], bfr[4];
#pragma unroll
        for (int i = 0; i < 4; ++i)
            af[i] = *(const short8*)&As[(wr * 64 + i * 16 + lm) * 32 + quad * 8];
#pragma unroll
        for (int j = 0; j < 4; ++j)
            bfr[j] = *(const short8*)&Bs[(wc * 64 + j * 16 + lm) * 32 + quad * 8];
#pragma unroll
        for (int i = 0; i < 4; ++i)
#pragma unroll
            for (int j = 0; j < 4; ++j)
                acc[i][j] = __builtin_amdgcn_mfma_f32_16x16x32_bf16(
                    af[i], bfr[j], acc[i][j], 0, 0, 0);
    }
#pragma unroll
    for (int i = 0; i < 4; ++i)
#pragma unroll
        for (int j = 0; j < 4; ++j) {
            const int n = n0 + wc * 64 + j * 16 + lm;
#pragma unroll
            for (int r = 0; r < 4; ++r) {
                const int m = m0 + wr * 64 + i * 16 + quad * 4 + r;
                C[(size_t)m * NN + n] = acc[i][j][r];
            }
        }
}

extern "C" void kernel_launch(void* const* d_in, const int* in_sizes, int n_in,
                              void* d_out, int out_size, void* d_ws, size_t ws_size,
                              hipStream_t stream) {
    const float* A = (const float*)d_in[0];  // [8,8192,512]
    const float* B = (const float*)d_in[1];  // [8,1024,512]
    float* C = (float*)d_out;                // [8192,1024]

    if (ws_size >= WS_NEEDED) {
        short* Abf = (short*)d_ws;
        short* Bbf = Abf + A_ELEMS;
        cvt_f32_bf16<<<CVT_NBLOCKS, 256, 0, stream>>>(A, B, Abf, Bbf);
        dim3 grid(NN / BN, MM / BM);  // (8, 64) = 512 blocks
        gemm_bf16_rs<<<grid, 256, 0, stream>>>(Abf, Bbf, C);
    } else {
        dim3 grid(NN / 128, MM / 128);  // (8, 64)
        gemm_rs_fused<<<grid, 256, 0, stream>>>(A, B, C);
    }
}